// Round 5
// baseline (568.946 us; speedup 1.0000x reference)
//
#include <hip/hip_runtime.h>

// SharedSparseMoEBlock on gfx950 — round 5: sparse path + fast aux chain.
// r4 -> r5: transpose fused into router, parallel bin scan, finalize folded
// into final_add. moe_sparse unchanged from r4 (201 us, proven).

typedef __bf16 bf16x8 __attribute__((ext_vector_type(8)));
typedef unsigned short u16x8 __attribute__((ext_vector_type(8)));
typedef float f32x4 __attribute__((ext_vector_type(4)));

#define HWP 9216      // 96*96
#define NPIX 73728    // 8*9216
#define LDX 136       // xs pitch in u16
#define LDH 136       // hs pitch in u16
#define MAXSLOTS 77312   // 73728 + 56*64 padding headroom
#define MAXTILES 1208    // MAXSLOTS/64

__device__ __forceinline__ unsigned short f2bf(float f) {
    unsigned u = __float_as_uint(f);
    u += 0x7fffu + ((u >> 16) & 1u);   // RNE
    return (unsigned short)(u >> 16);
}

__device__ __forceinline__ unsigned pk_bf16(float a, float b) {
    return (unsigned)f2bf(a) | ((unsigned)f2bf(b) << 16);
}

// tanh-approx GELU
__device__ __forceinline__ float fast_gelu(float x) {
    float x2 = x * x;
    float u = x * fmaf(0.0356774081f, x2, 0.7978845608f);
    float e = __builtin_amdgcn_exp2f(u * 2.8853900818f);
    float r = __builtin_amdgcn_rcpf(e + 1.0f);
    float t = fmaf(-2.0f, r, 1.0f);
    float s = 0.5f * x;
    return fmaf(s, t, s);
}

__device__ __forceinline__ f32x4 mfma16(u16x8 a, u16x8 b, f32x4 c) {
    return __builtin_amdgcn_mfma_f32_16x16x32_bf16(
        __builtin_bit_cast(bf16x8, a), __builtin_bit_cast(bf16x8, b), c, 0, 0, 0);
}

__global__ __launch_bounds__(256) void convert_weights(
    const float* __restrict__ sw1, const float* __restrict__ sw2,
    const float* __restrict__ ew1, const float* __restrict__ ew2,
    unsigned short* __restrict__ dst)
{
    int i = blockIdx.x * 256 + threadIdx.x;   // grid exactly 1179648
    float v;
    if (i < 65536) v = sw1[i];
    else if (i < 131072) v = sw2[i - 65536];
    else if (i < 655360) v = ew1[i - 131072];
    else v = ew2[i - 655360];
    dst[i] = f2bf(v);
}

// Fused: reads x once (coalesced), writes xT [pix][C] bf16, computes router
// (softmax/top-3/renorm), bins pixels, accumulates aux sums.
// Block = 64 pixels x 4 channel-quarters.
__global__ __launch_bounds__(256) void router_fused(
    const float* __restrict__ x, const float* __restrict__ gw,
    const float* __restrict__ gb,
    unsigned short* __restrict__ xT,
    int* __restrict__ pixmask, float* __restrict__ pixw3,
    int* __restrict__ bincount, float* __restrict__ accum)
{
    __shared__ float gws[8 * 128];
    __shared__ unsigned short xls[64 * 132];
    __shared__ float part[4 * 64 * 8];

    const int tid = threadIdx.x;
    for (int i = tid; i < 1024; i += 256) gws[i] = gw[i];
    __syncthreads();

    const int blk = blockIdx.x;               // grid = 1152
    const int b = blk / 144;
    const int p0 = (blk - b * 144) * 64;
    const int p = tid & 63, q = tid >> 6;
    const float* xb = x + (size_t)b * 128 * HWP + p0 + p;

    float lg[8];
    #pragma unroll
    for (int e = 0; e < 8; ++e) lg[e] = 0.f;
    #pragma unroll
    for (int k = 0; k < 32; ++k) {
        int c = q * 32 + k;
        float xv = xb[(size_t)c * HWP];       // coalesced across lanes (p)
        xls[p * 132 + c] = f2bf(xv);
        #pragma unroll
        for (int e = 0; e < 8; ++e) lg[e] = fmaf(xv, gws[e * 128 + c], lg[e]);
    }
    #pragma unroll
    for (int e = 0; e < 8; ++e) part[(q * 64 + p) * 8 + e] = lg[e];
    __syncthreads();

    if (tid < 64) {                            // wave 0: one pixel per lane
        const int gp = b * HWP + p0 + tid;
        float l2[8];
        #pragma unroll
        for (int e = 0; e < 8; ++e)
            l2[e] = gb[e] + part[tid * 8 + e] + part[(64 + tid) * 8 + e]
                  + part[(128 + tid) * 8 + e] + part[(192 + tid) * 8 + e];
        float mx = l2[0];
        #pragma unroll
        for (int e = 1; e < 8; ++e) mx = fmaxf(mx, l2[e]);
        float pr[8]; float s = 0.f;
        #pragma unroll
        for (int e = 0; e < 8; ++e) { pr[e] = __expf(l2[e] - mx); s += pr[e]; }
        float sinv = __builtin_amdgcn_rcpf(s);
        #pragma unroll
        for (int e = 0; e < 8; ++e) pr[e] *= sinv;

        // top-3, first-index wins ties (matches lax.top_k)
        unsigned chosen = 0; float topsum = 0.f;
        for (int k = 0; k < 3; ++k) {
            int best = 0; float bv = -1.f;
            #pragma unroll
            for (int e = 0; e < 8; ++e) {
                bool ok = !((chosen >> e) & 1u) && pr[e] > bv;
                bv = ok ? pr[e] : bv;
                best = ok ? e : best;
            }
            chosen |= 1u << best;
            topsum += bv;
        }
        float tinv = __builtin_amdgcn_rcpf(topsum);

        pixmask[gp] = (int)chosen;
        {   // weights in ascending-expert order
            int j = 0;
            #pragma unroll
            for (int e = 0; e < 8; ++e)
                if ((chosen >> e) & 1u) { pixw3[gp * 3 + j] = pr[e] * tinv; ++j; }
        }
        atomicAdd(&bincount[chosen], 1);

        // aux: full-wave (64-lane) shuffle reduce, lane 0 -> 16 global atomics
        #pragma unroll
        for (int e = 0; e < 8; ++e) {
            float v = pr[e];
            float cnt = ((chosen >> e) & 1u) ? 1.f : 0.f;
            #pragma unroll
            for (int off = 32; off > 0; off >>= 1) {
                v += __shfl_down(v, off);
                cnt += __shfl_down(cnt, off);
            }
            if (tid == 0) {
                atomicAdd(&accum[e], v);
                atomicAdd(&accum[8 + e], cnt);
            }
        }
    }

    // xls is read-only after the first barrier; no extra barrier needed.
    {
        const int pp = tid >> 2, qq = tid & 3;
        unsigned short* dst = xT + ((size_t)blk * 64 + pp) * 128 + qq * 32;
        const unsigned short* src = &xls[pp * 132 + qq * 32];
        #pragma unroll
        for (int j = 0; j < 4; ++j) *(u16x8*)(dst + j * 8) = *(const u16x8*)(src + j * 8);
    }
}

// Parallel: 256 threads, one bin each. LDS Hillis-Steele scan.
__global__ __launch_bounds__(256) void scan_bins(
    const int* __restrict__ bincount, int* __restrict__ binbase,
    int* __restrict__ tileMask, int* __restrict__ tileBase,
    int* __restrict__ ntiles, int* __restrict__ idx)
{
    __shared__ int spc[256], snt[256];
    const int tid = threadIdx.x;
    const int c = bincount[tid];
    const int nt = (c + 63) >> 6;
    const int pc = nt << 6;
    spc[tid] = pc; snt[tid] = nt;
    __syncthreads();
    #pragma unroll
    for (int off = 1; off < 256; off <<= 1) {
        int a = (tid >= off) ? spc[tid - off] : 0;
        int d = (tid >= off) ? snt[tid - off] : 0;
        __syncthreads();
        spc[tid] += a; snt[tid] += d;
        __syncthreads();
    }
    const int base = spc[tid] - pc;       // exclusive prefix of padded counts
    const int tstart = snt[tid] - nt;     // exclusive prefix of tile counts
    binbase[tid] = base;
    for (int j = 0; j < nt; ++j) {
        tileMask[tstart + j] = tid;
        tileBase[tstart + j] = base + (j << 6);
    }
    if (tid == 255) ntiles[0] = snt[255];
    for (int s = tid; s < MAXSLOTS; s += 256) idx[s] = 0;  // pad slots -> pixel 0
}

__global__ __launch_bounds__(256) void fill_bins(
    const int* __restrict__ pixmask, const int* __restrict__ binbase,
    int* __restrict__ binfill, int* __restrict__ idx, int* __restrict__ pixslot)
{
    const int gp = blockIdx.x * 256 + threadIdx.x;   // grid exactly 73728
    int mask = pixmask[gp];
    int pos = atomicAdd(&binfill[mask], 1);
    int slot = binbase[mask] + pos;
    idx[slot] = gp;
    pixslot[gp] = slot;
}

__global__ __launch_bounds__(256, 3) void moe_sparse(
    const unsigned short* __restrict__ xT, const int* __restrict__ idx,
    const float* __restrict__ pixw3,
    const int* __restrict__ tileMask, const int* __restrict__ tileBase,
    const int* __restrict__ ntiles,
    const unsigned short* __restrict__ wsw1, const float* __restrict__ sb1,
    const unsigned short* __restrict__ wsw2, const float* __restrict__ sb2,
    const unsigned short* __restrict__ wew1, const float* __restrict__ eb1,
    const unsigned short* __restrict__ wew2, const float* __restrict__ eb2,
    float* __restrict__ outT)
{
    __shared__ unsigned short xs[64 * LDX];
    __shared__ unsigned short hs[64 * LDH];
    __shared__ float wls[64 * 4];

    const int t = blockIdx.x;
    if (t >= ntiles[0]) return;               // uniform early-exit for pad blocks
    const int mask = tileMask[t];
    const int base = tileBase[t];
    const int tid = threadIdx.x;

    {   // gather 64 pixel rows from xT (256 B/pixel, coalesced)
        const int p = tid >> 2, q = tid & 3;
        const int gp = idx[base + p];
        const unsigned short* src = xT + (size_t)gp * 128 + q * 32;
        unsigned short* dst = &xs[p * LDX + q * 32];
        #pragma unroll
        for (int j = 0; j < 4; ++j) *(u16x8*)(dst + j * 8) = *(const u16x8*)(src + j * 8);
        if (q == 0) {
            wls[p * 4 + 0] = pixw3[gp * 3 + 0];
            wls[p * 4 + 1] = pixw3[gp * 3 + 1];
            wls[p * 4 + 2] = pixw3[gp * 3 + 2];
        }
    }
    __syncthreads();

    int el[3];
    { int n = 0;
      #pragma unroll
      for (int e = 0; e < 8; ++e) if ((mask >> e) & 1) { if (n < 3) el[n] = e; ++n; } }

    const int wave = tid >> 6;
    const int lr = tid & 15;
    const int lq = (tid >> 4) & 3;

    const f32x4 vzero = {0.f, 0.f, 0.f, 0.f};
    f32x4 fin[2][4];
    #pragma unroll
    for (int t2 = 0; t2 < 2; ++t2)
        #pragma unroll
        for (int nt = 0; nt < 4; ++nt) fin[t2][nt] = vzero;

    for (int pass = 0; pass < 4; ++pass) {
        const unsigned short* w1; const unsigned short* w2;
        const float* b1; const float* b2;
        if (pass == 0) { w1 = wsw1; b1 = sb1; w2 = wsw2; b2 = sb2; }
        else {
            int e = el[pass - 1];
            w1 = wew1 + (size_t)e * (512 * 128);  b1 = eb1 + e * 512;
            w2 = wew2 + (size_t)e * (128 * 512);  b2 = eb2 + e * 128;
        }

        f32x4 tmp[2][4];
        #pragma unroll
        for (int t2 = 0; t2 < 2; ++t2)
            #pragma unroll
            for (int nt = 0; nt < 4; ++nt) tmp[t2][nt] = vzero;

        for (int chunk = 0; chunk < 4; ++chunk) {
            // GEMM1 (transposed): D[hid][pix]; A=w1 rows, B=xs rows
            u16x8 w1f[2][4];
            #pragma unroll
            for (int t2 = 0; t2 < 2; ++t2) {
                const int hid0 = chunk * 128 + wave * 32 + t2 * 16;
                const u16x8* wr = (const u16x8*)(w1 + (size_t)(hid0 + lr) * 128) + lq;
                #pragma unroll
                for (int ks = 0; ks < 4; ++ks) w1f[t2][ks] = wr[ks * 4];
            }
            f32x4 acc[2][4];
            #pragma unroll
            for (int t2 = 0; t2 < 2; ++t2)
                #pragma unroll
                for (int nt = 0; nt < 4; ++nt) acc[t2][nt] = vzero;
            #pragma unroll
            for (int ks = 0; ks < 4; ++ks) {
                #pragma unroll
                for (int nt = 0; nt < 4; ++nt) {
                    u16x8 xf = *(const u16x8*)&xs[(nt * 16 + lr) * LDX + ks * 32 + lq * 8];
                    acc[0][nt] = mfma16(w1f[0][ks], xf, acc[0][nt]);
                    acc[1][nt] = mfma16(w1f[1][ks], xf, acc[1][nt]);
                }
            }
            // bias + GELU -> hs[pix][hid-local]
            #pragma unroll
            for (int t2 = 0; t2 < 2; ++t2) {
                const int hl = wave * 32 + t2 * 16 + lq * 4;
                const f32x4 b1v = *(const f32x4*)&b1[chunk * 128 + hl];
                #pragma unroll
                for (int nt = 0; nt < 4; ++nt) {
                    float g0 = fast_gelu(acc[t2][nt][0] + b1v[0]);
                    float g1 = fast_gelu(acc[t2][nt][1] + b1v[1]);
                    float g2 = fast_gelu(acc[t2][nt][2] + b1v[2]);
                    float g3 = fast_gelu(acc[t2][nt][3] + b1v[3]);
                    uint2 wv = {pk_bf16(g0, g1), pk_bf16(g2, g3)};
                    *(uint2*)&hs[(nt * 16 + lr) * LDH + hl] = wv;
                }
            }
            __syncthreads();
            // GEMM2 (transposed): D[cout][pix]; A=w2 rows, B=hs rows
            u16x8 w2f[2][4];
            #pragma unroll
            for (int t2 = 0; t2 < 2; ++t2) {
                const int c0 = wave * 32 + t2 * 16;
                const u16x8* wr = (const u16x8*)(w2 + (size_t)(c0 + lr) * 512 + chunk * 128) + lq;
                #pragma unroll
                for (int ks = 0; ks < 4; ++ks) w2f[t2][ks] = wr[ks * 4];
            }
            #pragma unroll
            for (int ks = 0; ks < 4; ++ks) {
                #pragma unroll
                for (int nt = 0; nt < 4; ++nt) {
                    u16x8 hb = *(const u16x8*)&hs[(nt * 16 + lr) * LDH + ks * 32 + lq * 8];
                    tmp[0][nt] = mfma16(w2f[0][ks], hb, tmp[0][nt]);
                    tmp[1][nt] = mfma16(w2f[1][ks], hb, tmp[1][nt]);
                }
            }
            __syncthreads();
        }
        // combine: fin += wt_pix * (tmp + b2); pixel = nt*16+lr (lane-uniform weight)
        float wtv[4];
        #pragma unroll
        for (int nt = 0; nt < 4; ++nt)
            wtv[nt] = (pass == 0) ? 1.0f : wls[(nt * 16 + lr) * 4 + (pass - 1)];
        #pragma unroll
        for (int t2 = 0; t2 < 2; ++t2) {
            const f32x4 b2v = *(const f32x4*)&b2[wave * 32 + t2 * 16 + lq * 4];
            #pragma unroll
            for (int nt = 0; nt < 4; ++nt)
                #pragma unroll
                for (int r = 0; r < 4; ++r)
                    fin[t2][nt][r] += wtv[nt] * (tmp[t2][nt][r] + b2v[r]);
        }
    }

    // write combined rows to outT[slot][cout] (f32x4, slot-contiguous)
    #pragma unroll
    for (int t2 = 0; t2 < 2; ++t2)
        #pragma unroll
        for (int nt = 0; nt < 4; ++nt) {
            float* dst = outT + ((size_t)(base + nt * 16 + lr)) * 128
                       + wave * 32 + t2 * 16 + lq * 4;
            *(f32x4*)dst = fin[t2][nt];
        }
}

__global__ __launch_bounds__(256) void final_add(
    const float* __restrict__ x, const float* __restrict__ outT,
    const int* __restrict__ pixslot, const float* __restrict__ accum,
    float* __restrict__ out)
{
    if (blockIdx.x == 0 && threadIdx.x == 0) {   // aux loss (accum final since router)
        float aux = 0.f;
        #pragma unroll
        for (int e = 0; e < 8; ++e) aux += accum[e] * accum[8 + e];
        out[9437184] = 8.0f * aux / ((float)NPIX * (float)NPIX);
    }
    __shared__ float ts[64 * 133];
    const int blk = blockIdx.x;               // 1152
    const int b = blk / 144;
    const int p0 = (blk - b * 144) * 64;
    const int tid = threadIdx.x;
    {   // gather this tile's combined rows
        const int p = tid >> 2, q = tid & 3;
        const int slot = pixslot[blk * 64 + p];
        const float* src = outT + (size_t)slot * 128 + q * 32;
        float* dst = &ts[p * 133 + q * 32];
        #pragma unroll
        for (int j = 0; j < 8; ++j) ((f32x4*)dst)[j] = ((const f32x4*)src)[j];
    }
    __syncthreads();
    const int pl = tid & 63, cq = tid >> 6;
    const float* xb = x + (size_t)b * 128 * HWP + p0;
    float* ob = out + (size_t)b * 128 * HWP + p0;
    #pragma unroll
    for (int c0 = 0; c0 < 128; c0 += 4) {
        int c = c0 + cq;
        ob[(size_t)c * HWP + pl] = xb[(size_t)c * HWP + pl] + ts[pl * 133 + c];
    }
}

extern "C" void kernel_launch(void* const* d_in, const int* in_sizes, int n_in,
                              void* d_out, int out_size, void* d_ws, size_t ws_size,
                              hipStream_t stream)
{
    const float* x   = (const float*)d_in[0];
    const float* sw1 = (const float*)d_in[1];
    const float* sb1 = (const float*)d_in[2];
    const float* sw2 = (const float*)d_in[3];
    const float* sb2 = (const float*)d_in[4];
    const float* gw  = (const float*)d_in[5];
    const float* gb  = (const float*)d_in[6];
    const float* ew1 = (const float*)d_in[7];
    const float* eb1 = (const float*)d_in[8];
    const float* ew2 = (const float*)d_in[9];
    const float* eb2 = (const float*)d_in[10];
    float* out = (float*)d_out;
    char* ws = (char*)d_ws;

    const size_t o_wbf     = 0;                      // 2359296
    const size_t o_xT      = 2359296;                // 18874368
    const size_t o_outT    = o_xT + 18874368;        // 39583744
    const size_t o_pixmask = o_outT + 39583744;      // 294912
    const size_t o_pixw3   = o_pixmask + 294912;     // 884736
    const size_t o_pixslot = o_pixw3 + 884736;       // 294912
    const size_t o_idx     = o_pixslot + 294912;     // 309248
    const size_t o_tmask   = o_idx + 309248;         // 4864
    const size_t o_tbase   = o_tmask + 4864;         // 4864
    const size_t o_binbase = o_tbase + 4864;         // 1024
    const size_t o_cnt     = o_binbase + 1024;       // 1024 (bincount)
    const size_t o_fill    = o_cnt + 1024;           // 1024 (binfill)
    const size_t o_ntiles  = o_fill + 1024;          // 16
    const size_t o_accum   = o_ntiles + 16;          // 64

    unsigned short* wbf = (unsigned short*)(ws + o_wbf);
    unsigned short* xT  = (unsigned short*)(ws + o_xT);
    float* outT   = (float*)(ws + o_outT);
    int* pixmask  = (int*)(ws + o_pixmask);
    float* pixw3  = (float*)(ws + o_pixw3);
    int* pixslot  = (int*)(ws + o_pixslot);
    int* idx      = (int*)(ws + o_idx);
    int* tmask    = (int*)(ws + o_tmask);
    int* tbase    = (int*)(ws + o_tbase);
    int* binbase  = (int*)(ws + o_binbase);
    int* bincount = (int*)(ws + o_cnt);
    int* binfill  = (int*)(ws + o_fill);
    int* ntiles   = (int*)(ws + o_ntiles);
    float* accum  = (float*)(ws + o_accum);

    (void)hipMemsetAsync(ws + o_cnt, 0, 1024 + 1024 + 16 + 64, stream);
    convert_weights<<<4608, 256, 0, stream>>>(sw1, sw2, ew1, ew2, wbf);
    router_fused<<<1152, 256, 0, stream>>>(x, gw, gb, xT, pixmask, pixw3, bincount, accum);
    scan_bins<<<1, 256, 0, stream>>>(bincount, binbase, tmask, tbase, ntiles, idx);
    fill_bins<<<288, 256, 0, stream>>>(pixmask, binbase, binfill, idx, pixslot);
    moe_sparse<<<MAXTILES, 256, 0, stream>>>(xT, idx, pixw3, tmask, tbase, ntiles,
        wbf, sb1, wbf + 65536, sb2, wbf + 131072, eb1, wbf + 655360, eb2, outT);
    final_add<<<1152, 256, 0, stream>>>(x, outT, pixslot, accum, out);
}

// Round 6
// 506.154 us; speedup vs baseline: 1.1241x; 1.1241x over previous
//
#include <hip/hip_runtime.h>

// SharedSparseMoEBlock on gfx950 — round 6: kill fill_bins atomic contention.
// r5 -> r6: wave-level ballot aggregation in router (1 atomic per block per
// distinct mask, not per pixel); fill_bins is atomic-free. moe_sparse unchanged.

typedef __bf16 bf16x8 __attribute__((ext_vector_type(8)));
typedef unsigned short u16x8 __attribute__((ext_vector_type(8)));
typedef float f32x4 __attribute__((ext_vector_type(4)));

#define HWP 9216      // 96*96
#define NPIX 73728    // 8*9216
#define LDX 136       // xs pitch in u16
#define LDH 136       // hs pitch in u16
#define MAXSLOTS 77312   // 73728 + 56*64 padding headroom
#define MAXTILES 1208    // MAXSLOTS/64

__device__ __forceinline__ unsigned short f2bf(float f) {
    unsigned u = __float_as_uint(f);
    u += 0x7fffu + ((u >> 16) & 1u);   // RNE
    return (unsigned short)(u >> 16);
}

__device__ __forceinline__ unsigned pk_bf16(float a, float b) {
    return (unsigned)f2bf(a) | ((unsigned)f2bf(b) << 16);
}

// tanh-approx GELU
__device__ __forceinline__ float fast_gelu(float x) {
    float x2 = x * x;
    float u = x * fmaf(0.0356774081f, x2, 0.7978845608f);
    float e = __builtin_amdgcn_exp2f(u * 2.8853900818f);
    float r = __builtin_amdgcn_rcpf(e + 1.0f);
    float t = fmaf(-2.0f, r, 1.0f);
    float s = 0.5f * x;
    return fmaf(s, t, s);
}

__device__ __forceinline__ f32x4 mfma16(u16x8 a, u16x8 b, f32x4 c) {
    return __builtin_amdgcn_mfma_f32_16x16x32_bf16(
        __builtin_bit_cast(bf16x8, a), __builtin_bit_cast(bf16x8, b), c, 0, 0, 0);
}

__global__ __launch_bounds__(256) void convert_weights(
    const float* __restrict__ sw1, const float* __restrict__ sw2,
    const float* __restrict__ ew1, const float* __restrict__ ew2,
    unsigned short* __restrict__ dst)
{
    int i = blockIdx.x * 256 + threadIdx.x;   // grid exactly 1179648
    float v;
    if (i < 65536) v = sw1[i];
    else if (i < 131072) v = sw2[i - 65536];
    else if (i < 655360) v = ew1[i - 131072];
    else v = ew2[i - 655360];
    dst[i] = f2bf(v);
}

// Fused: reads x once (coalesced), writes xT [pix][C] bf16, computes router
// (softmax/top-3/renorm), ballot-bins pixels, accumulates aux sums.
__global__ __launch_bounds__(256) void router_fused(
    const float* __restrict__ x, const float* __restrict__ gw,
    const float* __restrict__ gb,
    unsigned short* __restrict__ xT,
    int* __restrict__ pixmask, float* __restrict__ pixw3,
    int* __restrict__ pixaux,          // bin-relative rank (later reused as slot)
    int* __restrict__ bincount, float* __restrict__ accum)
{
    __shared__ float gws[8 * 128];
    __shared__ unsigned short xls[64 * 132];
    __shared__ float part[4 * 64 * 8];

    const int tid = threadIdx.x;
    for (int i = tid; i < 1024; i += 256) gws[i] = gw[i];
    __syncthreads();

    const int blk = blockIdx.x;               // grid = 1152
    const int b = blk / 144;
    const int p0 = (blk - b * 144) * 64;
    const int p = tid & 63, q = tid >> 6;
    const float* xb = x + (size_t)b * 128 * HWP + p0 + p;

    float lg[8];
    #pragma unroll
    for (int e = 0; e < 8; ++e) lg[e] = 0.f;
    #pragma unroll
    for (int k = 0; k < 32; ++k) {
        int c = q * 32 + k;
        float xv = xb[(size_t)c * HWP];       // coalesced across lanes (p)
        xls[p * 132 + c] = f2bf(xv);
        #pragma unroll
        for (int e = 0; e < 8; ++e) lg[e] = fmaf(xv, gws[e * 128 + c], lg[e]);
    }
    #pragma unroll
    for (int e = 0; e < 8; ++e) part[(q * 64 + p) * 8 + e] = lg[e];
    __syncthreads();

    if (tid < 64) {                            // wave 0: one pixel per lane
        const int gp = b * HWP + p0 + tid;
        float l2[8];
        #pragma unroll
        for (int e = 0; e < 8; ++e)
            l2[e] = gb[e] + part[tid * 8 + e] + part[(64 + tid) * 8 + e]
                  + part[(128 + tid) * 8 + e] + part[(192 + tid) * 8 + e];
        float mx = l2[0];
        #pragma unroll
        for (int e = 1; e < 8; ++e) mx = fmaxf(mx, l2[e]);
        float pr[8]; float s = 0.f;
        #pragma unroll
        for (int e = 0; e < 8; ++e) { pr[e] = __expf(l2[e] - mx); s += pr[e]; }
        float sinv = __builtin_amdgcn_rcpf(s);
        #pragma unroll
        for (int e = 0; e < 8; ++e) pr[e] *= sinv;

        // top-3, first-index wins ties (matches lax.top_k)
        unsigned chosen = 0; float topsum = 0.f;
        for (int k = 0; k < 3; ++k) {
            int best = 0; float bv = -1.f;
            #pragma unroll
            for (int e = 0; e < 8; ++e) {
                bool ok = !((chosen >> e) & 1u) && pr[e] > bv;
                bv = ok ? pr[e] : bv;
                best = ok ? e : best;
            }
            chosen |= 1u << best;
            topsum += bv;
        }
        float tinv = __builtin_amdgcn_rcpf(topsum);

        pixmask[gp] = (int)chosen;
        {   // weights in ascending-expert order
            int j = 0;
            #pragma unroll
            for (int e = 0; e < 8; ++e)
                if ((chosen >> e) & 1u) { pixw3[gp * 3 + j] = pr[e] * tinv; ++j; }
        }

        // ballot equality-classes over the 8-bit mask -> one atomic per class
        unsigned long long eq = ~0ull;
        #pragma unroll
        for (int bit = 0; bit < 8; ++bit) {
            unsigned long long bb = __ballot((chosen >> bit) & 1u);
            eq &= ((chosen >> bit) & 1u) ? bb : ~bb;
        }
        const unsigned long long lowmask = (tid == 0) ? 0ull : (~0ull >> (64 - tid));
        int rank = __popcll(eq & lowmask);
        int cnt = __popcll(eq);
        int leader = __ffsll((unsigned long long)eq) - 1;
        int off_val = 0;
        if (rank == 0) off_val = atomicAdd(&bincount[chosen], cnt);
        int binoff = __shfl(off_val, leader);
        pixaux[gp] = binoff + rank;            // bin-relative position

        // aux: full-wave shuffle reduce, lane 0 -> 16 global atomics
        #pragma unroll
        for (int e = 0; e < 8; ++e) {
            float v = pr[e];
            float c2 = ((chosen >> e) & 1u) ? 1.f : 0.f;
            #pragma unroll
            for (int off = 32; off > 0; off >>= 1) {
                v += __shfl_down(v, off);
                c2 += __shfl_down(c2, off);
            }
            if (tid == 0) {
                atomicAdd(&accum[e], v);
                atomicAdd(&accum[8 + e], c2);
            }
        }
    }

    // xls is read-only after the first barrier; no extra barrier needed.
    {
        const int pp = tid >> 2, qq = tid & 3;
        unsigned short* dst = xT + ((size_t)blk * 64 + pp) * 128 + qq * 32;
        const unsigned short* src = &xls[pp * 132 + qq * 32];
        #pragma unroll
        for (int j = 0; j < 4; ++j) *(u16x8*)(dst + j * 8) = *(const u16x8*)(src + j * 8);
    }
}

// Parallel: 256 threads, one bin each. LDS Hillis-Steele scan.
__global__ __launch_bounds__(256) void scan_bins(
    const int* __restrict__ bincount, int* __restrict__ binbase,
    int* __restrict__ tileMask, int* __restrict__ tileBase,
    int* __restrict__ ntiles, int* __restrict__ idx)
{
    __shared__ int spc[256], snt[256];
    const int tid = threadIdx.x;
    const int c = bincount[tid];
    const int nt = (c + 63) >> 6;
    const int pc = nt << 6;
    spc[tid] = pc; snt[tid] = nt;
    __syncthreads();
    #pragma unroll
    for (int off = 1; off < 256; off <<= 1) {
        int a = (tid >= off) ? spc[tid - off] : 0;
        int d = (tid >= off) ? snt[tid - off] : 0;
        __syncthreads();
        spc[tid] += a; snt[tid] += d;
        __syncthreads();
    }
    const int base = spc[tid] - pc;       // exclusive prefix of padded counts
    const int tstart = snt[tid] - nt;     // exclusive prefix of tile counts
    binbase[tid] = base;
    for (int j = 0; j < nt; ++j) {
        tileMask[tstart + j] = tid;
        tileBase[tstart + j] = base + (j << 6);
    }
    if (tid == 255) ntiles[0] = snt[255];
    for (int s = tid; s < MAXSLOTS; s += 256) idx[s] = 0;  // pad slots -> pixel 0
}

// Atomic-free: slot = binbase[mask] + rank (computed in router).
__global__ __launch_bounds__(256) void fill_bins(
    const int* __restrict__ pixmask, const int* __restrict__ binbase,
    int* __restrict__ idx, int* __restrict__ pixaux)
{
    const int gp = blockIdx.x * 256 + threadIdx.x;   // grid exactly 73728
    int mask = pixmask[gp];
    int slot = binbase[mask] + pixaux[gp];
    idx[slot] = gp;
    pixaux[gp] = slot;                                // reuse as pixslot
}

__global__ __launch_bounds__(256, 3) void moe_sparse(
    const unsigned short* __restrict__ xT, const int* __restrict__ idx,
    const float* __restrict__ pixw3,
    const int* __restrict__ tileMask, const int* __restrict__ tileBase,
    const int* __restrict__ ntiles,
    const unsigned short* __restrict__ wsw1, const float* __restrict__ sb1,
    const unsigned short* __restrict__ wsw2, const float* __restrict__ sb2,
    const unsigned short* __restrict__ wew1, const float* __restrict__ eb1,
    const unsigned short* __restrict__ wew2, const float* __restrict__ eb2,
    float* __restrict__ outT)
{
    __shared__ unsigned short xs[64 * LDX];
    __shared__ unsigned short hs[64 * LDH];
    __shared__ float wls[64 * 4];

    const int t = blockIdx.x;
    if (t >= ntiles[0]) return;               // uniform early-exit for pad blocks
    const int mask = tileMask[t];
    const int base = tileBase[t];
    const int tid = threadIdx.x;

    {   // gather 64 pixel rows from xT (256 B/pixel, coalesced)
        const int p = tid >> 2, q = tid & 3;
        const int gp = idx[base + p];
        const unsigned short* src = xT + (size_t)gp * 128 + q * 32;
        unsigned short* dst = &xs[p * LDX + q * 32];
        #pragma unroll
        for (int j = 0; j < 4; ++j) *(u16x8*)(dst + j * 8) = *(const u16x8*)(src + j * 8);
        if (q == 0) {
            wls[p * 4 + 0] = pixw3[gp * 3 + 0];
            wls[p * 4 + 1] = pixw3[gp * 3 + 1];
            wls[p * 4 + 2] = pixw3[gp * 3 + 2];
        }
    }
    __syncthreads();

    int el[3];
    { int n = 0;
      #pragma unroll
      for (int e = 0; e < 8; ++e) if ((mask >> e) & 1) { if (n < 3) el[n] = e; ++n; } }

    const int wave = tid >> 6;
    const int lr = tid & 15;
    const int lq = (tid >> 4) & 3;

    const f32x4 vzero = {0.f, 0.f, 0.f, 0.f};
    f32x4 fin[2][4];
    #pragma unroll
    for (int t2 = 0; t2 < 2; ++t2)
        #pragma unroll
        for (int nt = 0; nt < 4; ++nt) fin[t2][nt] = vzero;

    for (int pass = 0; pass < 4; ++pass) {
        const unsigned short* w1; const unsigned short* w2;
        const float* b1; const float* b2;
        if (pass == 0) { w1 = wsw1; b1 = sb1; w2 = wsw2; b2 = sb2; }
        else {
            int e = el[pass - 1];
            w1 = wew1 + (size_t)e * (512 * 128);  b1 = eb1 + e * 512;
            w2 = wew2 + (size_t)e * (128 * 512);  b2 = eb2 + e * 128;
        }

        f32x4 tmp[2][4];
        #pragma unroll
        for (int t2 = 0; t2 < 2; ++t2)
            #pragma unroll
            for (int nt = 0; nt < 4; ++nt) tmp[t2][nt] = vzero;

        for (int chunk = 0; chunk < 4; ++chunk) {
            // GEMM1 (transposed): D[hid][pix]; A=w1 rows, B=xs rows
            u16x8 w1f[2][4];
            #pragma unroll
            for (int t2 = 0; t2 < 2; ++t2) {
                const int hid0 = chunk * 128 + wave * 32 + t2 * 16;
                const u16x8* wr = (const u16x8*)(w1 + (size_t)(hid0 + lr) * 128) + lq;
                #pragma unroll
                for (int ks = 0; ks < 4; ++ks) w1f[t2][ks] = wr[ks * 4];
            }
            f32x4 acc[2][4];
            #pragma unroll
            for (int t2 = 0; t2 < 2; ++t2)
                #pragma unroll
                for (int nt = 0; nt < 4; ++nt) acc[t2][nt] = vzero;
            #pragma unroll
            for (int ks = 0; ks < 4; ++ks) {
                #pragma unroll
                for (int nt = 0; nt < 4; ++nt) {
                    u16x8 xf = *(const u16x8*)&xs[(nt * 16 + lr) * LDX + ks * 32 + lq * 8];
                    acc[0][nt] = mfma16(w1f[0][ks], xf, acc[0][nt]);
                    acc[1][nt] = mfma16(w1f[1][ks], xf, acc[1][nt]);
                }
            }
            // bias + GELU -> hs[pix][hid-local]
            #pragma unroll
            for (int t2 = 0; t2 < 2; ++t2) {
                const int hl = wave * 32 + t2 * 16 + lq * 4;
                const f32x4 b1v = *(const f32x4*)&b1[chunk * 128 + hl];
                #pragma unroll
                for (int nt = 0; nt < 4; ++nt) {
                    float g0 = fast_gelu(acc[t2][nt][0] + b1v[0]);
                    float g1 = fast_gelu(acc[t2][nt][1] + b1v[1]);
                    float g2 = fast_gelu(acc[t2][nt][2] + b1v[2]);
                    float g3 = fast_gelu(acc[t2][nt][3] + b1v[3]);
                    uint2 wv = {pk_bf16(g0, g1), pk_bf16(g2, g3)};
                    *(uint2*)&hs[(nt * 16 + lr) * LDH + hl] = wv;
                }
            }
            __syncthreads();
            // GEMM2 (transposed): D[cout][pix]; A=w2 rows, B=hs rows
            u16x8 w2f[2][4];
            #pragma unroll
            for (int t2 = 0; t2 < 2; ++t2) {
                const int c0 = wave * 32 + t2 * 16;
                const u16x8* wr = (const u16x8*)(w2 + (size_t)(c0 + lr) * 512 + chunk * 128) + lq;
                #pragma unroll
                for (int ks = 0; ks < 4; ++ks) w2f[t2][ks] = wr[ks * 4];
            }
            #pragma unroll
            for (int ks = 0; ks < 4; ++ks) {
                #pragma unroll
                for (int nt = 0; nt < 4; ++nt) {
                    u16x8 hb = *(const u16x8*)&hs[(nt * 16 + lr) * LDH + ks * 32 + lq * 8];
                    tmp[0][nt] = mfma16(w2f[0][ks], hb, tmp[0][nt]);
                    tmp[1][nt] = mfma16(w2f[1][ks], hb, tmp[1][nt]);
                }
            }
            __syncthreads();
        }
        // combine: fin += wt_pix * (tmp + b2); pixel = nt*16+lr (lane-uniform weight)
        float wtv[4];
        #pragma unroll
        for (int nt = 0; nt < 4; ++nt)
            wtv[nt] = (pass == 0) ? 1.0f : wls[(nt * 16 + lr) * 4 + (pass - 1)];
        #pragma unroll
        for (int t2 = 0; t2 < 2; ++t2) {
            const f32x4 b2v = *(const f32x4*)&b2[wave * 32 + t2 * 16 + lq * 4];
            #pragma unroll
            for (int nt = 0; nt < 4; ++nt)
                #pragma unroll
                for (int r = 0; r < 4; ++r)
                    fin[t2][nt][r] += wtv[nt] * (tmp[t2][nt][r] + b2v[r]);
        }
    }

    // write combined rows to outT[slot][cout] (f32x4, slot-contiguous)
    #pragma unroll
    for (int t2 = 0; t2 < 2; ++t2)
        #pragma unroll
        for (int nt = 0; nt < 4; ++nt) {
            float* dst = outT + ((size_t)(base + nt * 16 + lr)) * 128
                       + wave * 32 + t2 * 16 + lq * 4;
            *(f32x4*)dst = fin[t2][nt];
        }
}

__global__ __launch_bounds__(256) void final_add(
    const float* __restrict__ x, const float* __restrict__ outT,
    const int* __restrict__ pixslot, const float* __restrict__ accum,
    float* __restrict__ out)
{
    if (blockIdx.x == 0 && threadIdx.x == 0) {   // aux loss (accum final since router)
        float aux = 0.f;
        #pragma unroll
        for (int e = 0; e < 8; ++e) aux += accum[e] * accum[8 + e];
        out[9437184] = 8.0f * aux / ((float)NPIX * (float)NPIX);
    }
    __shared__ float ts[64 * 133];
    const int blk = blockIdx.x;               // 1152
    const int b = blk / 144;
    const int p0 = (blk - b * 144) * 64;
    const int tid = threadIdx.x;
    {   // gather this tile's combined rows
        const int p = tid >> 2, q = tid & 3;
        const int slot = pixslot[blk * 64 + p];
        const float* src = outT + (size_t)slot * 128 + q * 32;
        float* dst = &ts[p * 133 + q * 32];
        #pragma unroll
        for (int j = 0; j < 8; ++j) ((f32x4*)dst)[j] = ((const f32x4*)src)[j];
    }
    __syncthreads();
    const int pl = tid & 63, cq = tid >> 6;
    const float* xb = x + (size_t)b * 128 * HWP + p0;
    float* ob = out + (size_t)b * 128 * HWP + p0;
    #pragma unroll
    for (int c0 = 0; c0 < 128; c0 += 4) {
        int c = c0 + cq;
        ob[(size_t)c * HWP + pl] = xb[(size_t)c * HWP + pl] + ts[pl * 133 + c];
    }
}

extern "C" void kernel_launch(void* const* d_in, const int* in_sizes, int n_in,
                              void* d_out, int out_size, void* d_ws, size_t ws_size,
                              hipStream_t stream)
{
    const float* x   = (const float*)d_in[0];
    const float* sw1 = (const float*)d_in[1];
    const float* sb1 = (const float*)d_in[2];
    const float* sw2 = (const float*)d_in[3];
    const float* sb2 = (const float*)d_in[4];
    const float* gw  = (const float*)d_in[5];
    const float* gb  = (const float*)d_in[6];
    const float* ew1 = (const float*)d_in[7];
    const float* eb1 = (const float*)d_in[8];
    const float* ew2 = (const float*)d_in[9];
    const float* eb2 = (const float*)d_in[10];
    float* out = (float*)d_out;
    char* ws = (char*)d_ws;

    const size_t o_wbf     = 0;                      // 2359296
    const size_t o_xT      = 2359296;                // 18874368
    const size_t o_outT    = o_xT + 18874368;        // 39583744
    const size_t o_pixmask = o_outT + 39583744;      // 294912
    const size_t o_pixw3   = o_pixmask + 294912;     // 884736
    const size_t o_pixaux  = o_pixw3 + 884736;       // 294912 (rank -> slot)
    const size_t o_idx     = o_pixaux + 294912;      // 309248
    const size_t o_tmask   = o_idx + 309248;         // 4864
    const size_t o_tbase   = o_tmask + 4864;         // 4864
    const size_t o_binbase = o_tbase + 4864;         // 1024
    const size_t o_cnt     = o_binbase + 1024;       // 1024 (bincount)
    const size_t o_ntiles  = o_cnt + 1024;           // 16
    const size_t o_accum   = o_ntiles + 16;          // 64

    unsigned short* wbf = (unsigned short*)(ws + o_wbf);
    unsigned short* xT  = (unsigned short*)(ws + o_xT);
    float* outT   = (float*)(ws + o_outT);
    int* pixmask  = (int*)(ws + o_pixmask);
    float* pixw3  = (float*)(ws + o_pixw3);
    int* pixaux   = (int*)(ws + o_pixaux);
    int* idx      = (int*)(ws + o_idx);
    int* tmask    = (int*)(ws + o_tmask);
    int* tbase    = (int*)(ws + o_tbase);
    int* binbase  = (int*)(ws + o_binbase);
    int* bincount = (int*)(ws + o_cnt);
    int* ntiles   = (int*)(ws + o_ntiles);
    float* accum  = (float*)(ws + o_accum);

    (void)hipMemsetAsync(ws + o_cnt, 0, 1024 + 16 + 64, stream);
    convert_weights<<<4608, 256, 0, stream>>>(sw1, sw2, ew1, ew2, wbf);
    router_fused<<<1152, 256, 0, stream>>>(x, gw, gb, xT, pixmask, pixw3, pixaux,
                                           bincount, accum);
    scan_bins<<<1, 256, 0, stream>>>(bincount, binbase, tmask, tbase, ntiles, idx);
    fill_bins<<<288, 256, 0, stream>>>(pixmask, binbase, idx, pixaux);
    moe_sparse<<<MAXTILES, 256, 0, stream>>>(xT, idx, pixw3, tmask, tbase, ntiles,
        wbf, sb1, wbf + 65536, sb2, wbf + 131072, eb1, wbf + 655360, eb2, outT);
    final_add<<<1152, 256, 0, stream>>>(x, outT, pixaux, accum, out);
}

// Round 7
// 489.339 us; speedup vs baseline: 1.1627x; 1.0344x over previous
//
#include <hip/hip_runtime.h>

// SharedSparseMoEBlock on gfx950 — round 7: collapse aux chain to 5 dispatches.
// r6 -> r7: convert fused into router; scan fused into fill (per-block LDS scan,
// block 0 emits tile list); idx zeroing via memset; outT stored as bf16.
// moe_sparse GEMM structure unchanged (proven 203 us).

typedef __bf16 bf16x8 __attribute__((ext_vector_type(8)));
typedef unsigned short u16x8 __attribute__((ext_vector_type(8)));
typedef float f32x4 __attribute__((ext_vector_type(4)));

#define HWP 9216      // 96*96
#define NPIX 73728    // 8*9216
#define LDX 136       // xs pitch in u16
#define LDH 136       // hs pitch in u16
#define MAXSLOTS 77312   // 73728 + 56*64 padding headroom
#define MAXTILES 1208    // MAXSLOTS/64

__device__ __forceinline__ unsigned short f2bf(float f) {
    unsigned u = __float_as_uint(f);
    u += 0x7fffu + ((u >> 16) & 1u);   // RNE
    return (unsigned short)(u >> 16);
}

__device__ __forceinline__ unsigned pk_bf16(float a, float b) {
    return (unsigned)f2bf(a) | ((unsigned)f2bf(b) << 16);
}

__device__ __forceinline__ float bf2f(unsigned short h) {
    unsigned u = (unsigned)h << 16;
    return __uint_as_float(u);
}

// tanh-approx GELU
__device__ __forceinline__ float fast_gelu(float x) {
    float x2 = x * x;
    float u = x * fmaf(0.0356774081f, x2, 0.7978845608f);
    float e = __builtin_amdgcn_exp2f(u * 2.8853900818f);
    float r = __builtin_amdgcn_rcpf(e + 1.0f);
    float t = fmaf(-2.0f, r, 1.0f);
    float s = 0.5f * x;
    return fmaf(s, t, s);
}

__device__ __forceinline__ f32x4 mfma16(u16x8 a, u16x8 b, f32x4 c) {
    return __builtin_amdgcn_mfma_f32_16x16x32_bf16(
        __builtin_bit_cast(bf16x8, a), __builtin_bit_cast(bf16x8, b), c, 0, 0, 0);
}

// Fused: weight conversion prologue + x staging (coalesced, one pass) + router
// (softmax/top-3/renorm) + ballot binning + aux sums + xT write.
__global__ __launch_bounds__(256) void router_fused(
    const float* __restrict__ x, const float* __restrict__ gw,
    const float* __restrict__ gb,
    const float* __restrict__ sw1, const float* __restrict__ sw2,
    const float* __restrict__ ew1, const float* __restrict__ ew2,
    unsigned short* __restrict__ wbf,
    unsigned short* __restrict__ xT,
    int* __restrict__ pixmask, float* __restrict__ pixw3,
    int* __restrict__ pixaux,          // bin-relative rank (later reused as slot)
    int* __restrict__ bincount, float* __restrict__ accum)
{
    __shared__ float gws[8 * 128];
    __shared__ unsigned short xls[64 * 132];
    __shared__ float part[4 * 64 * 8];

    const int tid = threadIdx.x;
    const int blk = blockIdx.x;               // grid = 1152

    {   // weight conversion: 1179648 elems / (1152*256) = 4 per thread
        int i = blk * 256 + tid;
        #pragma unroll
        for (int j = 0; j < 4; ++j) {
            float v;
            if (i < 65536) v = sw1[i];
            else if (i < 131072) v = sw2[i - 65536];
            else if (i < 655360) v = ew1[i - 131072];
            else v = ew2[i - 655360];
            wbf[i] = f2bf(v);
            i += 1152 * 256;
        }
    }

    for (int i = tid; i < 1024; i += 256) gws[i] = gw[i];
    __syncthreads();

    const int b = blk / 144;
    const int p0 = (blk - b * 144) * 64;
    const int p = tid & 63, q = tid >> 6;
    const float* xb = x + (size_t)b * 128 * HWP + p0 + p;

    float lg[8];
    #pragma unroll
    for (int e = 0; e < 8; ++e) lg[e] = 0.f;
    #pragma unroll
    for (int k = 0; k < 32; ++k) {
        int c = q * 32 + k;
        float xv = xb[(size_t)c * HWP];       // coalesced across lanes (p)
        xls[p * 132 + c] = f2bf(xv);
        #pragma unroll
        for (int e = 0; e < 8; ++e) lg[e] = fmaf(xv, gws[e * 128 + c], lg[e]);
    }
    #pragma unroll
    for (int e = 0; e < 8; ++e) part[(q * 64 + p) * 8 + e] = lg[e];
    __syncthreads();

    if (tid < 64) {                            // wave 0: one pixel per lane
        const int gp = b * HWP + p0 + tid;
        float l2[8];
        #pragma unroll
        for (int e = 0; e < 8; ++e)
            l2[e] = gb[e] + part[tid * 8 + e] + part[(64 + tid) * 8 + e]
                  + part[(128 + tid) * 8 + e] + part[(192 + tid) * 8 + e];
        float mx = l2[0];
        #pragma unroll
        for (int e = 1; e < 8; ++e) mx = fmaxf(mx, l2[e]);
        float pr[8]; float s = 0.f;
        #pragma unroll
        for (int e = 0; e < 8; ++e) { pr[e] = __expf(l2[e] - mx); s += pr[e]; }
        float sinv = __builtin_amdgcn_rcpf(s);
        #pragma unroll
        for (int e = 0; e < 8; ++e) pr[e] *= sinv;

        // top-3, first-index wins ties (matches lax.top_k)
        unsigned chosen = 0; float topsum = 0.f;
        for (int k = 0; k < 3; ++k) {
            int best = 0; float bv = -1.f;
            #pragma unroll
            for (int e = 0; e < 8; ++e) {
                bool ok = !((chosen >> e) & 1u) && pr[e] > bv;
                bv = ok ? pr[e] : bv;
                best = ok ? e : best;
            }
            chosen |= 1u << best;
            topsum += bv;
        }
        float tinv = __builtin_amdgcn_rcpf(topsum);

        pixmask[gp] = (int)chosen;
        {   // weights in ascending-expert order
            int j = 0;
            #pragma unroll
            for (int e = 0; e < 8; ++e)
                if ((chosen >> e) & 1u) { pixw3[gp * 3 + j] = pr[e] * tinv; ++j; }
        }

        // ballot equality-classes over the 8-bit mask -> one atomic per class
        unsigned long long eq = ~0ull;
        #pragma unroll
        for (int bit = 0; bit < 8; ++bit) {
            unsigned long long bb = __ballot((chosen >> bit) & 1u);
            eq &= ((chosen >> bit) & 1u) ? bb : ~bb;
        }
        const unsigned long long lowmask = (tid == 0) ? 0ull : (~0ull >> (64 - tid));
        int rank = __popcll(eq & lowmask);
        int cnt = __popcll(eq);
        int leader = __ffsll((unsigned long long)eq) - 1;
        int off_val = 0;
        if (rank == 0) off_val = atomicAdd(&bincount[chosen], cnt);
        int binoff = __shfl(off_val, leader);
        pixaux[gp] = binoff + rank;            // bin-relative position

        // aux: full-wave shuffle reduce, lane 0 -> 16 global atomics
        #pragma unroll
        for (int e = 0; e < 8; ++e) {
            float v = pr[e];
            float c2 = ((chosen >> e) & 1u) ? 1.f : 0.f;
            #pragma unroll
            for (int off = 32; off > 0; off >>= 1) {
                v += __shfl_down(v, off);
                c2 += __shfl_down(c2, off);
            }
            if (tid == 0) {
                atomicAdd(&accum[e], v);
                atomicAdd(&accum[8 + e], c2);
            }
        }
    }

    // xls is read-only after the first barrier; no extra barrier needed.
    {
        const int pp = tid >> 2, qq = tid & 3;
        unsigned short* dst = xT + ((size_t)blk * 64 + pp) * 128 + qq * 32;
        const unsigned short* src = &xls[pp * 132 + qq * 32];
        #pragma unroll
        for (int j = 0; j < 4; ++j) *(u16x8*)(dst + j * 8) = *(const u16x8*)(src + j * 8);
    }
}

// fill + scan fused: every block redoes the 256-bin scan in LDS (cheap,
// bincount is L2-broadcast); block 0 additionally emits the tile list.
__global__ __launch_bounds__(256) void fill_bins(
    const int* __restrict__ bincount, const int* __restrict__ pixmask,
    int* __restrict__ idx, int* __restrict__ pixaux,
    int* __restrict__ tileMask, int* __restrict__ tileBase,
    int* __restrict__ ntiles)
{
    __shared__ int spc[256], snt[256], bb[256];
    const int tid = threadIdx.x;
    const int c = bincount[tid];
    const int nt = (c + 63) >> 6;
    const int pc = nt << 6;
    spc[tid] = pc; snt[tid] = nt;
    __syncthreads();
    #pragma unroll
    for (int off = 1; off < 256; off <<= 1) {
        int a = (tid >= off) ? spc[tid - off] : 0;
        int d = (tid >= off) ? snt[tid - off] : 0;
        __syncthreads();
        spc[tid] += a; snt[tid] += d;
        __syncthreads();
    }
    const int base = spc[tid] - pc;       // exclusive prefix of padded counts
    bb[tid] = base;
    if (blockIdx.x == 0) {
        const int tstart = snt[tid] - nt; // exclusive prefix of tile counts
        for (int j = 0; j < nt; ++j) {
            tileMask[tstart + j] = tid;
            tileBase[tstart + j] = base + (j << 6);
        }
        if (tid == 255) ntiles[0] = snt[255];
    }
    __syncthreads();

    const int gp = blockIdx.x * 256 + tid;   // grid exactly 288*256 = 73728
    int mask = pixmask[gp];
    int slot = bb[mask] + pixaux[gp];
    idx[slot] = gp;                           // pad slots stay 0 (memset)
    pixaux[gp] = slot;                        // reuse as pixslot
}

__global__ __launch_bounds__(256, 3) void moe_sparse(
    const unsigned short* __restrict__ xT, const int* __restrict__ idx,
    const float* __restrict__ pixw3,
    const int* __restrict__ tileMask, const int* __restrict__ tileBase,
    const int* __restrict__ ntiles,
    const unsigned short* __restrict__ wsw1, const float* __restrict__ sb1,
    const unsigned short* __restrict__ wsw2, const float* __restrict__ sb2,
    const unsigned short* __restrict__ wew1, const float* __restrict__ eb1,
    const unsigned short* __restrict__ wew2, const float* __restrict__ eb2,
    unsigned short* __restrict__ outT)
{
    __shared__ unsigned short xs[64 * LDX];
    __shared__ unsigned short hs[64 * LDH];
    __shared__ float wls[64 * 4];

    const int t = blockIdx.x;
    if (t >= ntiles[0]) return;               // uniform early-exit for pad blocks
    const int mask = tileMask[t];
    const int base = tileBase[t];
    const int tid = threadIdx.x;

    {   // gather 64 pixel rows from xT (256 B/pixel, coalesced)
        const int p = tid >> 2, q = tid & 3;
        const int gp = idx[base + p];
        const unsigned short* src = xT + (size_t)gp * 128 + q * 32;
        unsigned short* dst = &xs[p * LDX + q * 32];
        #pragma unroll
        for (int j = 0; j < 4; ++j) *(u16x8*)(dst + j * 8) = *(const u16x8*)(src + j * 8);
        if (q == 0) {
            wls[p * 4 + 0] = pixw3[gp * 3 + 0];
            wls[p * 4 + 1] = pixw3[gp * 3 + 1];
            wls[p * 4 + 2] = pixw3[gp * 3 + 2];
        }
    }
    __syncthreads();

    int el[3];
    { int n = 0;
      #pragma unroll
      for (int e = 0; e < 8; ++e) if ((mask >> e) & 1) { if (n < 3) el[n] = e; ++n; } }

    const int wave = tid >> 6;
    const int lr = tid & 15;
    const int lq = (tid >> 4) & 3;

    const f32x4 vzero = {0.f, 0.f, 0.f, 0.f};
    f32x4 fin[2][4];
    #pragma unroll
    for (int t2 = 0; t2 < 2; ++t2)
        #pragma unroll
        for (int nt = 0; nt < 4; ++nt) fin[t2][nt] = vzero;

    for (int pass = 0; pass < 4; ++pass) {
        const unsigned short* w1; const unsigned short* w2;
        const float* b1; const float* b2;
        if (pass == 0) { w1 = wsw1; b1 = sb1; w2 = wsw2; b2 = sb2; }
        else {
            int e = el[pass - 1];
            w1 = wew1 + (size_t)e * (512 * 128);  b1 = eb1 + e * 512;
            w2 = wew2 + (size_t)e * (128 * 512);  b2 = eb2 + e * 128;
        }

        f32x4 tmp[2][4];
        #pragma unroll
        for (int t2 = 0; t2 < 2; ++t2)
            #pragma unroll
            for (int nt = 0; nt < 4; ++nt) tmp[t2][nt] = vzero;

        for (int chunk = 0; chunk < 4; ++chunk) {
            // GEMM1 (transposed): D[hid][pix]; A=w1 rows, B=xs rows
            u16x8 w1f[2][4];
            #pragma unroll
            for (int t2 = 0; t2 < 2; ++t2) {
                const int hid0 = chunk * 128 + wave * 32 + t2 * 16;
                const u16x8* wr = (const u16x8*)(w1 + (size_t)(hid0 + lr) * 128) + lq;
                #pragma unroll
                for (int ks = 0; ks < 4; ++ks) w1f[t2][ks] = wr[ks * 4];
            }
            f32x4 acc[2][4];
            #pragma unroll
            for (int t2 = 0; t2 < 2; ++t2)
                #pragma unroll
                for (int nt = 0; nt < 4; ++nt) acc[t2][nt] = vzero;
            #pragma unroll
            for (int ks = 0; ks < 4; ++ks) {
                #pragma unroll
                for (int nt = 0; nt < 4; ++nt) {
                    u16x8 xf = *(const u16x8*)&xs[(nt * 16 + lr) * LDX + ks * 32 + lq * 8];
                    acc[0][nt] = mfma16(w1f[0][ks], xf, acc[0][nt]);
                    acc[1][nt] = mfma16(w1f[1][ks], xf, acc[1][nt]);
                }
            }
            // bias + GELU -> hs[pix][hid-local]
            #pragma unroll
            for (int t2 = 0; t2 < 2; ++t2) {
                const int hl = wave * 32 + t2 * 16 + lq * 4;
                const f32x4 b1v = *(const f32x4*)&b1[chunk * 128 + hl];
                #pragma unroll
                for (int nt = 0; nt < 4; ++nt) {
                    float g0 = fast_gelu(acc[t2][nt][0] + b1v[0]);
                    float g1 = fast_gelu(acc[t2][nt][1] + b1v[1]);
                    float g2 = fast_gelu(acc[t2][nt][2] + b1v[2]);
                    float g3 = fast_gelu(acc[t2][nt][3] + b1v[3]);
                    uint2 wv = {pk_bf16(g0, g1), pk_bf16(g2, g3)};
                    *(uint2*)&hs[(nt * 16 + lr) * LDH + hl] = wv;
                }
            }
            __syncthreads();
            // GEMM2 (transposed): D[cout][pix]; A=w2 rows, B=hs rows
            u16x8 w2f[2][4];
            #pragma unroll
            for (int t2 = 0; t2 < 2; ++t2) {
                const int c0 = wave * 32 + t2 * 16;
                const u16x8* wr = (const u16x8*)(w2 + (size_t)(c0 + lr) * 512 + chunk * 128) + lq;
                #pragma unroll
                for (int ks = 0; ks < 4; ++ks) w2f[t2][ks] = wr[ks * 4];
            }
            #pragma unroll
            for (int ks = 0; ks < 4; ++ks) {
                #pragma unroll
                for (int nt = 0; nt < 4; ++nt) {
                    u16x8 hb = *(const u16x8*)&hs[(nt * 16 + lr) * LDH + ks * 32 + lq * 8];
                    tmp[0][nt] = mfma16(w2f[0][ks], hb, tmp[0][nt]);
                    tmp[1][nt] = mfma16(w2f[1][ks], hb, tmp[1][nt]);
                }
            }
            __syncthreads();
        }
        // combine: fin += wt_pix * (tmp + b2); pixel = nt*16+lr (lane-uniform weight)
        float wtv[4];
        #pragma unroll
        for (int nt = 0; nt < 4; ++nt)
            wtv[nt] = (pass == 0) ? 1.0f : wls[(nt * 16 + lr) * 4 + (pass - 1)];
        #pragma unroll
        for (int t2 = 0; t2 < 2; ++t2) {
            const f32x4 b2v = *(const f32x4*)&b2[wave * 32 + t2 * 16 + lq * 4];
            #pragma unroll
            for (int nt = 0; nt < 4; ++nt)
                #pragma unroll
                for (int r = 0; r < 4; ++r)
                    fin[t2][nt][r] += wtv[nt] * (tmp[t2][nt][r] + b2v[r]);
        }
    }

    // write combined rows to outT[slot][cout] as bf16 (8 B/lane, slot-contiguous)
    #pragma unroll
    for (int t2 = 0; t2 < 2; ++t2)
        #pragma unroll
        for (int nt = 0; nt < 4; ++nt) {
            unsigned short* dst = outT + ((size_t)(base + nt * 16 + lr)) * 128
                                + wave * 32 + t2 * 16 + lq * 4;
            uint2 wv = {pk_bf16(fin[t2][nt][0], fin[t2][nt][1]),
                        pk_bf16(fin[t2][nt][2], fin[t2][nt][3])};
            *(uint2*)dst = wv;
        }
}

__global__ __launch_bounds__(256) void final_add(
    const float* __restrict__ x, const unsigned short* __restrict__ outT,
    const int* __restrict__ pixslot, const float* __restrict__ accum,
    float* __restrict__ out)
{
    if (blockIdx.x == 0 && threadIdx.x == 0) {   // aux loss (accum final since router)
        float aux = 0.f;
        #pragma unroll
        for (int e = 0; e < 8; ++e) aux += accum[e] * accum[8 + e];
        out[9437184] = 8.0f * aux / ((float)NPIX * (float)NPIX);
    }
    __shared__ unsigned short ts[64 * 133];
    const int blk = blockIdx.x;               // 1152
    const int b = blk / 144;
    const int p0 = (blk - b * 144) * 64;
    const int tid = threadIdx.x;
    {   // gather this tile's combined rows (128 B/pixel bf16)
        const int p = tid >> 2, q = tid & 3;
        const int slot = pixslot[blk * 64 + p];
        const unsigned short* src = outT + (size_t)slot * 128 + q * 32;
        unsigned short* dst = &ts[p * 133 + q * 32];
        #pragma unroll
        for (int j = 0; j < 4; ++j) *(u16x8*)(dst + j * 8) = *(const u16x8*)(src + j * 8);
    }
    __syncthreads();
    const int pl = tid & 63, cq = tid >> 6;
    const float* xb = x + (size_t)b * 128 * HWP + p0;
    float* ob = out + (size_t)b * 128 * HWP + p0;
    #pragma unroll
    for (int c0 = 0; c0 < 128; c0 += 4) {
        int c = c0 + cq;
        ob[(size_t)c * HWP + pl] = xb[(size_t)c * HWP + pl] + bf2f(ts[pl * 133 + c]);
    }
}

extern "C" void kernel_launch(void* const* d_in, const int* in_sizes, int n_in,
                              void* d_out, int out_size, void* d_ws, size_t ws_size,
                              hipStream_t stream)
{
    const float* x   = (const float*)d_in[0];
    const float* sw1 = (const float*)d_in[1];
    const float* sb1 = (const float*)d_in[2];
    const float* sw2 = (const float*)d_in[3];
    const float* sb2 = (const float*)d_in[4];
    const float* gw  = (const float*)d_in[5];
    const float* gb  = (const float*)d_in[6];
    const float* ew1 = (const float*)d_in[7];
    const float* eb1 = (const float*)d_in[8];
    const float* ew2 = (const float*)d_in[9];
    const float* eb2 = (const float*)d_in[10];
    float* out = (float*)d_out;
    char* ws = (char*)d_ws;

    const size_t o_wbf     = 0;                       // 2359296
    const size_t o_xT      = 2359296;                 // 18874368
    const size_t o_outT    = o_xT + 18874368;         // MAXSLOTS*128*2 = 19791872
    const size_t o_pixmask = o_outT + 19791872;       // 294912
    const size_t o_pixw3   = o_pixmask + 294912;      // 884736
    const size_t o_pixaux  = o_pixw3 + 884736;        // 294912 (rank -> slot)
    const size_t o_tmask   = o_pixaux + 294912;       // 4864
    const size_t o_tbase   = o_tmask + 4864;          // 4864
    const size_t o_idx     = o_tbase + 4864;          // 309248  <-- memset from here
    const size_t o_cnt     = o_idx + 309248;          // 1024 (bincount)
    const size_t o_ntiles  = o_cnt + 1024;            // 16
    const size_t o_accum   = o_ntiles + 16;           // 64
    const size_t MEMSET_SZ = 309248 + 1024 + 16 + 64;

    unsigned short* wbf = (unsigned short*)(ws + o_wbf);
    unsigned short* xT  = (unsigned short*)(ws + o_xT);
    unsigned short* outT = (unsigned short*)(ws + o_outT);
    int* pixmask  = (int*)(ws + o_pixmask);
    float* pixw3  = (float*)(ws + o_pixw3);
    int* pixaux   = (int*)(ws + o_pixaux);
    int* tmask    = (int*)(ws + o_tmask);
    int* tbase    = (int*)(ws + o_tbase);
    int* idx      = (int*)(ws + o_idx);
    int* bincount = (int*)(ws + o_cnt);
    int* ntiles   = (int*)(ws + o_ntiles);
    float* accum  = (float*)(ws + o_accum);

    (void)hipMemsetAsync(ws + o_idx, 0, MEMSET_SZ, stream);
    router_fused<<<1152, 256, 0, stream>>>(x, gw, gb, sw1, sw2, ew1, ew2, wbf,
                                           xT, pixmask, pixw3, pixaux, bincount, accum);
    fill_bins<<<288, 256, 0, stream>>>(bincount, pixmask, idx, pixaux,
                                       tmask, tbase, ntiles);
    moe_sparse<<<MAXTILES, 256, 0, stream>>>(xT, idx, pixw3, tmask, tbase, ntiles,
        wbf, sb1, wbf + 65536, sb2, wbf + 131072, eb1, wbf + 655360, eb2, outT);
    final_add<<<1152, 256, 0, stream>>>(x, outT, pixaux, accum, out);
}